// Round 2
// baseline (563.935 us; speedup 1.0000x reference)
//
#include <hip/hip_runtime.h>

typedef __attribute__((ext_vector_type(8))) short bf16x8;
typedef __attribute__((ext_vector_type(4))) float f32x4;

#define TM 8           // tokens per block
#define CH 256

// ws layout (u16 elements): effective bf16 weight matrices, 256x256 each
#define WTT 0
#define WTD 65536
#define WVD 131072
#define WA  196608
#define WV  262144
#define WVN 327680

__device__ __forceinline__ unsigned short f2bf(float f) {
    unsigned u = __builtin_bit_cast(unsigned, f);
    u += 0x7FFFu + ((u >> 16) & 1u);        // RNE
    return (unsigned short)(u >> 16);
}

// ---------------- prep: Wa = Wtr(I+Wtt), Wv = Wdv(I-Wtt), bf16-convert all ----------------
__global__ __launch_bounds__(512)
void avd_prep_kernel(const float* __restrict__ Wtt, const float* __restrict__ Wtr,
                     const float* __restrict__ Wtd, const float* __restrict__ Wvd,
                     const float* __restrict__ Wdv, unsigned short* __restrict__ ws)
{
    __shared__ float ra[2][256], rv[2][256];
    const int half = threadIdx.x >> 8;          // 0..1
    const int c    = threadIdx.x & 255;
    const int o    = blockIdx.x * 2 + half;
    ra[half][c] = Wtr[o * 256 + c];
    rv[half][c] = Wdv[o * 256 + c];
    __syncthreads();
    float sa = 0.f, sv = 0.f;
    #pragma unroll 8
    for (int k = 0; k < 256; ++k) {
        float w = Wtt[k * 256 + c];             // coalesced across c
        sa += ra[half][k] * w;
        sv += rv[half][k] * w;
    }
    const int idx = o * 256 + c;
    const float wa = Wtr[idx] + sa;             // Wtr(I+Wtt)
    const float wv = Wdv[idx] - sv;             // Wdv(I-Wtt)
    ws[WA  + idx] = f2bf(wa);
    ws[WV  + idx] = f2bf(wv);
    ws[WVN + idx] = f2bf(-wv);
    ws[WTT + idx] = f2bf(Wtt[idx]);
    ws[WTD + idx] = f2bf(Wtd[idx]);
    ws[WVD + idx] = f2bf(Wvd[idx]);
}

// ---------------- main: single-layer fused ----------------
__global__ __launch_bounds__(512, 6)
void avd_main_kernel(const float* __restrict__ xa, const float* __restrict__ xv,
                     const float* __restrict__ xd,
                     const unsigned short* __restrict__ ws,
                     float* __restrict__ out)
{
    // slots 0..8: x_d (q = i*3+j); 9: x_a; 10..12: x_v comps. XOR-swizzled columns.
    __shared__ __attribute__((aligned(16))) unsigned short feat[13][TM][CH];

    const int tid  = threadIdx.x;
    const int lane = tid & 63;
    const int wid  = tid >> 6;          // 0..7
    const int m0   = blockIdx.x * TM;

    float* out_xa = out;                 // 16384*256
    float* out_xv = out + 4194304;       // + 16384*256*3
    float* out_xd = out + 16777216;      // + 16384*256*9

    // ---- stage x_d: 8*2304 floats = 4608 float4, 9 per thread ----
    {
        const float4* src = (const float4*)(xd + (size_t)m0 * 2304);
        #pragma unroll
        for (int it = 0; it < 9; ++it) {
            int i4 = tid + it * 512;
            float4 v = src[i4];
            float ve[4] = {v.x, v.y, v.z, v.w};
            int g = i4 * 4;
            #pragma unroll
            for (int e = 0; e < 4; ++e) {
                int gg  = g + e;
                int m   = gg / 2304;
                int rem = gg - m * 2304;
                int c   = rem / 9;
                int q   = rem - c * 9;
                feat[q][m][c ^ (m << 3)] = f2bf(ve[e]);
            }
        }
    }
    // ---- stage x_a: 512 float4, 1 per thread ----
    {
        float4 v = ((const float4*)(xa + (size_t)m0 * 256))[tid];
        int g = tid * 4;
        int m = g >> 8;
        int c = (g & 255) ^ (m << 3);   // 4 consecutive c stay contiguous under swizzle
        feat[9][m][c + 0] = f2bf(v.x);
        feat[9][m][c + 1] = f2bf(v.y);
        feat[9][m][c + 2] = f2bf(v.z);
        feat[9][m][c + 3] = f2bf(v.w);
    }
    // ---- stage x_v: 1536 float4, 3 per thread ----
    {
        const float4* src = (const float4*)(xv + (size_t)m0 * 768);
        #pragma unroll
        for (int it = 0; it < 3; ++it) {
            int i4 = tid + it * 512;
            float4 v = src[i4];
            float ve[4] = {v.x, v.y, v.z, v.w};
            int g = i4 * 4;
            #pragma unroll
            for (int e = 0; e < 4; ++e) {
                int gg  = g + e;
                int m   = gg / 768;
                int rem = gg - m * 768;
                int c   = rem / 3;
                int i   = rem - c * 3;
                feat[10 + i][m][c ^ (m << 3)] = f2bf(ve[e]);
            }
        }
    }
    __syncthreads();

    const int am  = lane & 7;    // A-frag row (token), rows 8..15 duplicate 0..7
    const int aq  = lane >> 4;   // k-quarter
    const int col = lane & 15;   // B-frag column (output channel within tile)

    // two 16-wide o-tiles per wave, processed sequentially
    #pragma unroll 1
    for (int t = 0; t < 2; ++t) {
        const int o = wid * 32 + t * 16 + col;

        // acc 0..8: t[q]; 9: delta; 10..12: w (cross); 13: xa-delta; 14..16: xv-delta
        f32x4 acc[17];
        #pragma unroll
        for (int p = 0; p < 17; ++p) acc[p] = (f32x4){0.f, 0.f, 0.f, 0.f};

        #pragma unroll 2
        for (int ks = 0; ks < 8; ++ks) {
            const int c0  = ks * 32 + aq * 8;
            const int csw = c0 ^ (am << 3);
            bf16x8 a[13];
            #pragma unroll
            for (int p = 0; p < 13; ++p)
                a[p] = *(const bf16x8*)&feat[p][am][csw];

            const int wb = o * 256 + c0;
            bf16x8 b_tt = *(const bf16x8*)(ws + WTT + wb);
            bf16x8 b_td = *(const bf16x8*)(ws + WTD + wb);
            bf16x8 b_vd = *(const bf16x8*)(ws + WVD + wb);
            bf16x8 b_wa = *(const bf16x8*)(ws + WA  + wb);
            bf16x8 b_wv = *(const bf16x8*)(ws + WV  + wb);
            bf16x8 b_wn = *(const bf16x8*)(ws + WVN + wb);

            #pragma unroll
            for (int q = 0; q < 9; ++q)
                acc[q] = __builtin_amdgcn_mfma_f32_16x16x32_bf16(a[q], b_tt, acc[q], 0, 0, 0);
            acc[9]  = __builtin_amdgcn_mfma_f32_16x16x32_bf16(a[9],  b_td, acc[9],  0, 0, 0);
            acc[10] = __builtin_amdgcn_mfma_f32_16x16x32_bf16(a[10], b_vd, acc[10], 0, 0, 0);
            acc[11] = __builtin_amdgcn_mfma_f32_16x16x32_bf16(a[11], b_vd, acc[11], 0, 0, 0);
            acc[12] = __builtin_amdgcn_mfma_f32_16x16x32_bf16(a[12], b_vd, acc[12], 0, 0, 0);
            // xa-delta: Wa @ (d0+d4+d8)
            acc[13] = __builtin_amdgcn_mfma_f32_16x16x32_bf16(a[0], b_wa, acc[13], 0, 0, 0);
            acc[13] = __builtin_amdgcn_mfma_f32_16x16x32_bf16(a[4], b_wa, acc[13], 0, 0, 0);
            acc[13] = __builtin_amdgcn_mfma_f32_16x16x32_bf16(a[8], b_wa, acc[13], 0, 0, 0);
            // xv-delta k: Wv @ (d_p - d_q) via +Wv / -Wv
            acc[14] = __builtin_amdgcn_mfma_f32_16x16x32_bf16(a[5], b_wv, acc[14], 0, 0, 0);
            acc[14] = __builtin_amdgcn_mfma_f32_16x16x32_bf16(a[7], b_wn, acc[14], 0, 0, 0);
            acc[15] = __builtin_amdgcn_mfma_f32_16x16x32_bf16(a[6], b_wv, acc[15], 0, 0, 0);
            acc[15] = __builtin_amdgcn_mfma_f32_16x16x32_bf16(a[2], b_wn, acc[15], 0, 0, 0);
            acc[16] = __builtin_amdgcn_mfma_f32_16x16x32_bf16(a[1], b_wv, acc[16], 0, 0, 0);
            acc[16] = __builtin_amdgcn_mfma_f32_16x16x32_bf16(a[3], b_wn, acc[16], 0, 0, 0);
        }

        // epilogue: lane holds (m = (lane>>4)*4 + r, o); valid rows m<8 -> lanes 0..31
        if (lane < 32) {
            #pragma unroll
            for (int r = 0; r < 4; ++r) {
                const int m = (lane >> 4) * 4 + r;
                const size_t row = (size_t)(m0 + m) * 256 + o;
                const float* dp = xd + row * 9;
                float d[9], tt[9];
                #pragma unroll
                for (int q = 0; q < 9; ++q) { d[q] = dp[q]; tt[q] = acc[q][r]; }
                const float delta = acc[9][r];
                const float w0 = acc[10][r], w1 = acc[11][r], w2 = acc[12][r];
                float* po = out_xd + row * 9;
                po[0] = d[0] + tt[0] + delta;
                po[1] = d[1] + tt[3] - w2;
                po[2] = d[2] + tt[6] + w1;
                po[3] = d[3] + tt[1] + w2;
                po[4] = d[4] + tt[4] + delta;
                po[5] = d[5] + tt[7] - w0;
                po[6] = d[6] + tt[2] - w1;
                po[7] = d[7] + tt[5] + w0;
                po[8] = d[8] + tt[8] + delta;
                out_xa[row] = xa[row] + acc[13][r];
                const size_t vrow = row * 3;
                out_xv[vrow + 0] = xv[vrow + 0] + acc[14][r];
                out_xv[vrow + 1] = xv[vrow + 1] + acc[15][r];
                out_xv[vrow + 2] = xv[vrow + 2] + acc[16][r];
            }
        }
    }
}

extern "C" void kernel_launch(void* const* d_in, const int* in_sizes, int n_in,
                              void* d_out, int out_size, void* d_ws, size_t ws_size,
                              hipStream_t stream) {
    const float* xa  = (const float*)d_in[0];
    const float* xv  = (const float*)d_in[1];
    const float* xd  = (const float*)d_in[2];
    const float* Wtt = (const float*)d_in[3];
    const float* Wtr = (const float*)d_in[4];
    const float* Wtd = (const float*)d_in[5];
    const float* Wvd = (const float*)d_in[6];
    const float* Wdv = (const float*)d_in[7];
    unsigned short* ws = (unsigned short*)d_ws;
    float* out = (float*)d_out;

    avd_prep_kernel<<<dim3(128), dim3(512), 0, stream>>>(Wtt, Wtr, Wtd, Wvd, Wdv, ws);
    avd_main_kernel<<<dim3(16384 / TM), dim3(512), 0, stream>>>(xa, xv, xd, ws, out);
}

// Round 4
// 271.934 us; speedup vs baseline: 2.0738x; 2.0738x over previous
//
#include <hip/hip_runtime.h>

typedef __attribute__((ext_vector_type(8))) short bf16x8;
typedef __attribute__((ext_vector_type(8))) unsigned short u16x8;
typedef __attribute__((ext_vector_type(4))) float f32x4;

#define TM 8           // tokens per block
#define CH 256

// ws layout (u16 elements): effective bf16 weight matrices, 256x256 each
#define WTT 0
#define WTD 65536
#define WVD 131072
#define WA  196608
#define WV  262144
#define WVN 327680

__device__ __forceinline__ unsigned short f2bf(float f) {
    unsigned u = __builtin_bit_cast(unsigned, f);
    u += 0x7FFFu + ((u >> 16) & 1u);        // RNE
    return (unsigned short)(u >> 16);
}
__device__ __forceinline__ float bf2f(unsigned short h) {
    return __builtin_bit_cast(float, (unsigned)h << 16);
}

// ---------------- prep: Wa = Wtr(I+Wtt), Wv = Wdv(I-Wtt), bf16-convert all ----------------
__global__ __launch_bounds__(512)
void avd_prep_kernel(const float* __restrict__ Wtt, const float* __restrict__ Wtr,
                     const float* __restrict__ Wtd, const float* __restrict__ Wvd,
                     const float* __restrict__ Wdv, unsigned short* __restrict__ ws)
{
    __shared__ float ra[2][256], rv[2][256];
    const int half = threadIdx.x >> 8;          // 0..1
    const int c    = threadIdx.x & 255;
    const int o    = blockIdx.x * 2 + half;
    ra[half][c] = Wtr[o * 256 + c];
    rv[half][c] = Wdv[o * 256 + c];
    __syncthreads();
    float sa = 0.f, sv = 0.f;
    #pragma unroll 8
    for (int k = 0; k < 256; ++k) {
        float w = Wtt[k * 256 + c];             // coalesced across c
        sa += ra[half][k] * w;
        sv += rv[half][k] * w;
    }
    const int idx = o * 256 + c;
    const float wa = Wtr[idx] + sa;             // Wtr(I+Wtt)
    const float wv = Wdv[idx] - sv;             // Wdv(I-Wtt)
    ws[WA  + idx] = f2bf(wa);
    ws[WV  + idx] = f2bf(wv);
    ws[WVN + idx] = f2bf(-wv);
    ws[WTT + idx] = f2bf(Wtt[idx]);
    ws[WTD + idx] = f2bf(Wtd[idx]);
    ws[WVD + idx] = f2bf(Wvd[idx]);
}

// ---------------- main: single-layer fused ----------------
__global__ __launch_bounds__(512, 4)
void avd_main_kernel(const float* __restrict__ xa, const float* __restrict__ xv,
                     const float* __restrict__ xd,
                     const unsigned short* __restrict__ ws,
                     float* __restrict__ out)
{
    // slots 0..8: x_d (q = i*3+j); 9: x_a; 10..12: x_v comps. XOR-swizzled columns.
    __shared__ __attribute__((aligned(16))) unsigned short feat[13][TM][CH];
    // xd-out staging for one o-half: [token][128 o x 9 q] bf16
    __shared__ __attribute__((aligned(16))) unsigned short ostage[TM][1152];

    const int tid  = threadIdx.x;
    const int lane = tid & 63;
    const int wid  = tid >> 6;          // 0..7
    const int m0   = blockIdx.x * TM;

    float* out_xa = out;                 // 16384*256
    float* out_xv = out + 4194304;       // + 16384*256*3
    float* out_xd = out + 16777216;      // + 16384*256*9

    // ---- stage x_d: 8*2304 floats = 4608 float4, 9 per thread ----
    {
        const f32x4* src = (const f32x4*)(xd + (size_t)m0 * 2304);
        #pragma unroll
        for (int it = 0; it < 9; ++it) {
            int i4 = tid + it * 512;
            f32x4 v = __builtin_nontemporal_load(&src[i4]);
            int g = i4 * 4;
            #pragma unroll
            for (int e = 0; e < 4; ++e) {
                int gg  = g + e;
                int m   = gg / 2304;
                int rem = gg - m * 2304;
                int c   = rem / 9;
                int q   = rem - c * 9;
                feat[q][m][c ^ (m << 3)] = f2bf(v[e]);
            }
        }
    }
    // ---- stage x_a: 512 float4, 1 per thread ----
    {
        f32x4 v = __builtin_nontemporal_load(&((const f32x4*)(xa + (size_t)m0 * 256))[tid]);
        int g = tid * 4;
        int m = g >> 8;
        int c = (g & 255) ^ (m << 3);   // 4 consecutive c stay contiguous under swizzle
        feat[9][m][c + 0] = f2bf(v[0]);
        feat[9][m][c + 1] = f2bf(v[1]);
        feat[9][m][c + 2] = f2bf(v[2]);
        feat[9][m][c + 3] = f2bf(v[3]);
    }
    // ---- stage x_v: 1536 float4, 3 per thread ----
    {
        const f32x4* src = (const f32x4*)(xv + (size_t)m0 * 768);
        #pragma unroll
        for (int it = 0; it < 3; ++it) {
            int i4 = tid + it * 512;
            f32x4 v = __builtin_nontemporal_load(&src[i4]);
            int g = i4 * 4;
            #pragma unroll
            for (int e = 0; e < 4; ++e) {
                int gg  = g + e;
                int m   = gg / 768;
                int rem = gg - m * 768;
                int c   = rem / 3;
                int i   = rem - c * 3;
                feat[10 + i][m][c ^ (m << 3)] = f2bf(v[e]);
            }
        }
    }
    __syncthreads();

    const int am  = lane & 7;    // A-frag row (token), rows 8..15 duplicate 0..7
    const int aq  = lane >> 4;   // k-quarter
    const int col = lane & 15;   // B-frag column (output channel within tile)

    // t=0 covers o in [0,128), t=1 covers [128,256): all waves participate per half
    #pragma unroll 1
    for (int t = 0; t < 2; ++t) {
        const int o = t * 128 + wid * 16 + col;

        // acc 0..8: t[q]; 9: delta; 10..12: w (cross); 13: xa-delta; 14..16: xv-delta
        f32x4 acc[17];
        #pragma unroll
        for (int p = 0; p < 17; ++p) acc[p] = (f32x4){0.f, 0.f, 0.f, 0.f};

        #pragma unroll 2
        for (int ks = 0; ks < 8; ++ks) {
            const int c0  = ks * 32 + aq * 8;
            const int csw = c0 ^ (am << 3);
            bf16x8 a[13];
            #pragma unroll
            for (int p = 0; p < 13; ++p)
                a[p] = *(const bf16x8*)&feat[p][am][csw];

            const int wb = o * 256 + c0;
            bf16x8 b_tt = *(const bf16x8*)(ws + WTT + wb);
            bf16x8 b_td = *(const bf16x8*)(ws + WTD + wb);
            bf16x8 b_vd = *(const bf16x8*)(ws + WVD + wb);
            bf16x8 b_wa = *(const bf16x8*)(ws + WA  + wb);
            bf16x8 b_wv = *(const bf16x8*)(ws + WV  + wb);
            bf16x8 b_wn = *(const bf16x8*)(ws + WVN + wb);

            #pragma unroll
            for (int q = 0; q < 9; ++q)
                acc[q] = __builtin_amdgcn_mfma_f32_16x16x32_bf16(a[q], b_tt, acc[q], 0, 0, 0);
            acc[9]  = __builtin_amdgcn_mfma_f32_16x16x32_bf16(a[9],  b_td, acc[9],  0, 0, 0);
            acc[10] = __builtin_amdgcn_mfma_f32_16x16x32_bf16(a[10], b_vd, acc[10], 0, 0, 0);
            acc[11] = __builtin_amdgcn_mfma_f32_16x16x32_bf16(a[11], b_vd, acc[11], 0, 0, 0);
            acc[12] = __builtin_amdgcn_mfma_f32_16x16x32_bf16(a[12], b_vd, acc[12], 0, 0, 0);
            // xa-delta: Wa @ (d0+d4+d8)
            acc[13] = __builtin_amdgcn_mfma_f32_16x16x32_bf16(a[0], b_wa, acc[13], 0, 0, 0);
            acc[13] = __builtin_amdgcn_mfma_f32_16x16x32_bf16(a[4], b_wa, acc[13], 0, 0, 0);
            acc[13] = __builtin_amdgcn_mfma_f32_16x16x32_bf16(a[8], b_wa, acc[13], 0, 0, 0);
            // xv-delta k: Wv @ (d_p - d_q) via +Wv / -Wv
            acc[14] = __builtin_amdgcn_mfma_f32_16x16x32_bf16(a[5], b_wv, acc[14], 0, 0, 0);
            acc[14] = __builtin_amdgcn_mfma_f32_16x16x32_bf16(a[7], b_wn, acc[14], 0, 0, 0);
            acc[15] = __builtin_amdgcn_mfma_f32_16x16x32_bf16(a[6], b_wv, acc[15], 0, 0, 0);
            acc[15] = __builtin_amdgcn_mfma_f32_16x16x32_bf16(a[2], b_wn, acc[15], 0, 0, 0);
            acc[16] = __builtin_amdgcn_mfma_f32_16x16x32_bf16(a[1], b_wv, acc[16], 0, 0, 0);
            acc[16] = __builtin_amdgcn_mfma_f32_16x16x32_bf16(a[3], b_wn, acc[16], 0, 0, 0);
        }

        // epilogue: lane holds (m = (lane>>4)*4 + r, o); valid rows m<8 -> lanes 0..31
        if (lane < 32) {
            const int ol9 = (o & 127) * 9;
            #pragma unroll
            for (int r = 0; r < 4; ++r) {
                const int m   = (lane >> 4) * 4 + r;
                const int csw = o ^ (m << 3);
                float d[9];
                #pragma unroll
                for (int q = 0; q < 9; ++q) d[q] = bf2f(feat[q][m][csw]);
                const float delta = acc[9][r];
                const float w0 = acc[10][r], w1 = acc[11][r], w2 = acc[12][r];
                unsigned short* os = &ostage[m][ol9];
                os[0] = f2bf(d[0] + acc[0][r] + delta);
                os[1] = f2bf(d[1] + acc[3][r] - w2);
                os[2] = f2bf(d[2] + acc[6][r] + w1);
                os[3] = f2bf(d[3] + acc[1][r] + w2);
                os[4] = f2bf(d[4] + acc[4][r] + delta);
                os[5] = f2bf(d[5] + acc[7][r] - w0);
                os[6] = f2bf(d[6] + acc[2][r] - w1);
                os[7] = f2bf(d[7] + acc[5][r] + w0);
                os[8] = f2bf(d[8] + acc[8][r] + delta);
                const size_t row = (size_t)(m0 + m) * 256 + o;
                __builtin_nontemporal_store(bf2f(feat[9][m][csw]) + acc[13][r], &out_xa[row]);
                const size_t vrow = row * 3;
                __builtin_nontemporal_store(bf2f(feat[10][m][csw]) + acc[14][r], &out_xv[vrow + 0]);
                __builtin_nontemporal_store(bf2f(feat[11][m][csw]) + acc[15][r], &out_xv[vrow + 1]);
                __builtin_nontemporal_store(bf2f(feat[12][m][csw]) + acc[16][r], &out_xv[vrow + 2]);
            }
        }
        __syncthreads();

        // drain ostage -> dense fp32 float4 stores (1152 floats per token half-row)
        {
            const u16x8* sp = (const u16x8*)&ostage[0][0];
            #pragma unroll
            for (int it = 0; it < 3; ++it) {
                int u8 = tid + it * 512;
                if (u8 < 1152) {
                    u16x8 h = sp[u8];
                    int fi  = u8 * 8;
                    int m   = fi / 1152;
                    int off = fi - m * 1152;
                    float* gp = out_xd + (size_t)(m0 + m) * 2304 + t * 1152 + off;
                    f32x4 lo = {bf2f(h[0]), bf2f(h[1]), bf2f(h[2]), bf2f(h[3])};
                    f32x4 hi = {bf2f(h[4]), bf2f(h[5]), bf2f(h[6]), bf2f(h[7])};
                    __builtin_nontemporal_store(lo, (f32x4*)gp);
                    __builtin_nontemporal_store(hi, (f32x4*)(gp + 4));
                }
            }
        }
        __syncthreads();
    }
}

extern "C" void kernel_launch(void* const* d_in, const int* in_sizes, int n_in,
                              void* d_out, int out_size, void* d_ws, size_t ws_size,
                              hipStream_t stream) {
    const float* xa  = (const float*)d_in[0];
    const float* xv  = (const float*)d_in[1];
    const float* xd  = (const float*)d_in[2];
    const float* Wtt = (const float*)d_in[3];
    const float* Wtr = (const float*)d_in[4];
    const float* Wtd = (const float*)d_in[5];
    const float* Wvd = (const float*)d_in[6];
    const float* Wdv = (const float*)d_in[7];
    unsigned short* ws = (unsigned short*)d_ws;
    float* out = (float*)d_out;

    avd_prep_kernel<<<dim3(128), dim3(512), 0, stream>>>(Wtt, Wtr, Wtd, Wvd, Wdv, ws);
    avd_main_kernel<<<dim3(16384 / TM), dim3(512), 0, stream>>>(xa, xv, xd, ws, out);
}

// Round 5
// 267.746 us; speedup vs baseline: 2.1062x; 1.0156x over previous
//
#include <hip/hip_runtime.h>

typedef __attribute__((ext_vector_type(8))) short bf16x8;
typedef __attribute__((ext_vector_type(8))) unsigned short u16x8;
typedef __attribute__((ext_vector_type(4))) float f32x4;

#define TM 8           // tokens per block
#define CH 256

// ws layout (u16 elements): effective bf16 weight matrices, 256x256 each
#define WTT 0
#define WTD 65536
#define WVD 131072
#define WA  196608
#define WV  262144
#define WVN 327680

__device__ __forceinline__ unsigned short f2bf(float f) {
    unsigned u = __builtin_bit_cast(unsigned, f);
    u += 0x7FFFu + ((u >> 16) & 1u);        // RNE
    return (unsigned short)(u >> 16);
}
__device__ __forceinline__ float bf2f(unsigned short h) {
    return __builtin_bit_cast(float, (unsigned)h << 16);
}

// ---------------- prep: Wa = Wtr(I+Wtt), Wv = Wdv(I-Wtt), bf16-convert all ----------------
__global__ __launch_bounds__(512)
void avd_prep_kernel(const float* __restrict__ Wtt, const float* __restrict__ Wtr,
                     const float* __restrict__ Wtd, const float* __restrict__ Wvd,
                     const float* __restrict__ Wdv, unsigned short* __restrict__ ws)
{
    __shared__ float ra[2][256], rv[2][256];
    const int half = threadIdx.x >> 8;          // 0..1
    const int c    = threadIdx.x & 255;
    const int o    = blockIdx.x * 2 + half;
    ra[half][c] = Wtr[o * 256 + c];
    rv[half][c] = Wdv[o * 256 + c];
    __syncthreads();
    float sa = 0.f, sv = 0.f;
    #pragma unroll 8
    for (int k = 0; k < 256; ++k) {
        float w = Wtt[k * 256 + c];             // coalesced across c
        sa += ra[half][k] * w;
        sv += rv[half][k] * w;
    }
    const int idx = o * 256 + c;
    const float wa = Wtr[idx] + sa;             // Wtr(I+Wtt)
    const float wv = Wdv[idx] - sv;             // Wdv(I-Wtt)
    ws[WA  + idx] = f2bf(wa);
    ws[WV  + idx] = f2bf(wv);
    ws[WVN + idx] = f2bf(-wv);
    ws[WTT + idx] = f2bf(Wtt[idx]);
    ws[WTD + idx] = f2bf(Wtd[idx]);
    ws[WVD + idx] = f2bf(Wvd[idx]);
}

// ---------------- main: single-layer fused ----------------
__global__ __launch_bounds__(512, 4)
void avd_main_kernel(const float* __restrict__ xa, const float* __restrict__ xv,
                     const float* __restrict__ xd,
                     const unsigned short* __restrict__ ws,
                     float* __restrict__ out)
{
    // slots 0..8: x_d (q = i*3+j); 9: x_a; 10..12: x_v comps. XOR-swizzled columns.
    __shared__ __attribute__((aligned(16))) unsigned short feat[13][TM][CH];   // 52 KB
    // per-o-half output staging (bf16), drained as dense fp32 streams
    __shared__ __attribute__((aligned(16))) unsigned short ostage[TM][1152];   // 18 KB xd
    __shared__ __attribute__((aligned(16))) unsigned short osA[TM][128];       //  2 KB xa
    __shared__ __attribute__((aligned(16))) unsigned short osV[TM][384];       //  6 KB xv

    const int tid  = threadIdx.x;
    const int lane = tid & 63;
    const int wid  = tid >> 6;          // 0..7
    const int m0   = blockIdx.x * TM;

    float* out_xa = out;                 // 16384*256
    float* out_xv = out + 4194304;       // + 16384*256*3
    float* out_xd = out + 16777216;      // + 16384*256*9

    // ---- stage: wave `wid` handles token m = wid; conflict-free u16 LDS writes ----
    {
        const int m   = wid;
        const int csw = lane ^ (m << 3);     // 64 consecutive u16, permuted in-block
        // x_d: [c][q] per token, stride-9 scalar reads; write c = lane + 64*cc
        const float* srcd = xd + (size_t)(m0 + m) * 2304;
        #pragma unroll
        for (int q = 0; q < 9; ++q)
            #pragma unroll
            for (int cc = 0; cc < 4; ++cc) {
                int c = lane + cc * 64;
                feat[q][m][csw ^ (cc << 6)] = f2bf(srcd[c * 9 + q]);
            }
        // x_v: [c][i], stride-3 scalar reads
        const float* srcv = xv + (size_t)(m0 + m) * 768;
        #pragma unroll
        for (int i = 0; i < 3; ++i)
            #pragma unroll
            for (int cc = 0; cc < 4; ++cc) {
                int c = lane + cc * 64;
                feat[10 + i][m][csw ^ (cc << 6)] = f2bf(srcv[c * 3 + i]);
            }
        // x_a: contiguous f32x4 per lane
        {
            f32x4 v = ((const f32x4*)(xa + (size_t)(m0 + m) * 256))[lane];
            #pragma unroll
            for (int e = 0; e < 4; ++e)
                feat[9][m][(lane * 4 + e) ^ (m << 3)] = f2bf(v[e]);
        }
    }
    __syncthreads();

    const int am  = lane & 7;    // A-frag row (token), rows 8..15 duplicate 0..7
    const int aq  = lane >> 4;   // k-quarter
    const int col = lane & 15;   // B-frag column (output channel within tile)

    // t=0 covers o in [0,128), t=1 covers [128,256)
    #pragma unroll 1
    for (int t = 0; t < 2; ++t) {
        const int o = t * 128 + wid * 16 + col;

        // acc 0..8: t[q]; 9: delta; 10..12: w (cross); 13: xa-delta; 14..16: xv-delta
        f32x4 acc[17];
        #pragma unroll
        for (int p = 0; p < 17; ++p) acc[p] = (f32x4){0.f, 0.f, 0.f, 0.f};

        #pragma unroll 2
        for (int ks = 0; ks < 8; ++ks) {
            const int c0  = ks * 32 + aq * 8;
            const int csw = c0 ^ (am << 3);
            bf16x8 a[13];
            #pragma unroll
            for (int p = 0; p < 13; ++p)
                a[p] = *(const bf16x8*)&feat[p][am][csw];

            const int wb = o * 256 + c0;
            bf16x8 b_tt = *(const bf16x8*)(ws + WTT + wb);
            bf16x8 b_td = *(const bf16x8*)(ws + WTD + wb);
            bf16x8 b_vd = *(const bf16x8*)(ws + WVD + wb);
            bf16x8 b_wa = *(const bf16x8*)(ws + WA  + wb);
            bf16x8 b_wv = *(const bf16x8*)(ws + WV  + wb);
            bf16x8 b_wn = *(const bf16x8*)(ws + WVN + wb);

            #pragma unroll
            for (int q = 0; q < 9; ++q)
                acc[q] = __builtin_amdgcn_mfma_f32_16x16x32_bf16(a[q], b_tt, acc[q], 0, 0, 0);
            acc[9]  = __builtin_amdgcn_mfma_f32_16x16x32_bf16(a[9],  b_td, acc[9],  0, 0, 0);
            acc[10] = __builtin_amdgcn_mfma_f32_16x16x32_bf16(a[10], b_vd, acc[10], 0, 0, 0);
            acc[11] = __builtin_amdgcn_mfma_f32_16x16x32_bf16(a[11], b_vd, acc[11], 0, 0, 0);
            acc[12] = __builtin_amdgcn_mfma_f32_16x16x32_bf16(a[12], b_vd, acc[12], 0, 0, 0);
            // xa-delta: Wa @ (d0+d4+d8)
            acc[13] = __builtin_amdgcn_mfma_f32_16x16x32_bf16(a[0], b_wa, acc[13], 0, 0, 0);
            acc[13] = __builtin_amdgcn_mfma_f32_16x16x32_bf16(a[4], b_wa, acc[13], 0, 0, 0);
            acc[13] = __builtin_amdgcn_mfma_f32_16x16x32_bf16(a[8], b_wa, acc[13], 0, 0, 0);
            // xv-delta k: Wv @ (d_p - d_q) via +Wv / -Wv
            acc[14] = __builtin_amdgcn_mfma_f32_16x16x32_bf16(a[5], b_wv, acc[14], 0, 0, 0);
            acc[14] = __builtin_amdgcn_mfma_f32_16x16x32_bf16(a[7], b_wn, acc[14], 0, 0, 0);
            acc[15] = __builtin_amdgcn_mfma_f32_16x16x32_bf16(a[6], b_wv, acc[15], 0, 0, 0);
            acc[15] = __builtin_amdgcn_mfma_f32_16x16x32_bf16(a[2], b_wn, acc[15], 0, 0, 0);
            acc[16] = __builtin_amdgcn_mfma_f32_16x16x32_bf16(a[1], b_wv, acc[16], 0, 0, 0);
            acc[16] = __builtin_amdgcn_mfma_f32_16x16x32_bf16(a[3], b_wn, acc[16], 0, 0, 0);
        }

        // epilogue -> LDS only (lane<32 holds valid rows m = (lane>>4)*4 + r)
        if (lane < 32) {
            const int ol = o & 127;
            #pragma unroll
            for (int r = 0; r < 4; ++r) {
                const int m   = (lane >> 4) * 4 + r;
                const int csw = o ^ (m << 3);
                float d[9];
                #pragma unroll
                for (int q = 0; q < 9; ++q) d[q] = bf2f(feat[q][m][csw]);
                const float delta = acc[9][r];
                const float w0 = acc[10][r], w1 = acc[11][r], w2 = acc[12][r];
                unsigned short* os = &ostage[m][ol * 9];
                os[0] = f2bf(d[0] + acc[0][r] + delta);
                os[1] = f2bf(d[1] + acc[3][r] - w2);
                os[2] = f2bf(d[2] + acc[6][r] + w1);
                os[3] = f2bf(d[3] + acc[1][r] + w2);
                os[4] = f2bf(d[4] + acc[4][r] + delta);
                os[5] = f2bf(d[5] + acc[7][r] - w0);
                os[6] = f2bf(d[6] + acc[2][r] - w1);
                os[7] = f2bf(d[7] + acc[5][r] + w0);
                os[8] = f2bf(d[8] + acc[8][r] + delta);
                osA[m][ol] = f2bf(bf2f(feat[9][m][csw]) + acc[13][r]);
                osV[m][ol * 3 + 0] = f2bf(bf2f(feat[10][m][csw]) + acc[14][r]);
                osV[m][ol * 3 + 1] = f2bf(bf2f(feat[11][m][csw]) + acc[15][r]);
                osV[m][ol * 3 + 2] = f2bf(bf2f(feat[12][m][csw]) + acc[16][r]);
            }
        }
        __syncthreads();

        // drain: dense nontemporal fp32 streams
        {
            // xa (128 u16x8) on threads 0..127, xv (384 u16x8) on threads 128..511
            if (tid < 128) {
                int m = tid >> 4, wi = tid & 15;
                u16x8 h = *(const u16x8*)&osA[m][wi * 8];
                float* gp = out_xa + (size_t)(m0 + m) * 256 + t * 128 + wi * 8;
                f32x4 lo, hi;
                lo[0]=bf2f(h[0]); lo[1]=bf2f(h[1]); lo[2]=bf2f(h[2]); lo[3]=bf2f(h[3]);
                hi[0]=bf2f(h[4]); hi[1]=bf2f(h[5]); hi[2]=bf2f(h[6]); hi[3]=bf2f(h[7]);
                __builtin_nontemporal_store(lo, (f32x4*)gp);
                __builtin_nontemporal_store(hi, (f32x4*)(gp + 4));
            } else {
                int v = tid - 128;
                int m = v / 48, wi = v - m * 48;
                u16x8 h = *(const u16x8*)&osV[m][wi * 8];
                float* gp = out_xv + (size_t)(m0 + m) * 768 + t * 384 + wi * 8;
                f32x4 lo, hi;
                lo[0]=bf2f(h[0]); lo[1]=bf2f(h[1]); lo[2]=bf2f(h[2]); lo[3]=bf2f(h[3]);
                hi[0]=bf2f(h[4]); hi[1]=bf2f(h[5]); hi[2]=bf2f(h[6]); hi[3]=bf2f(h[7]);
                __builtin_nontemporal_store(lo, (f32x4*)gp);
                __builtin_nontemporal_store(hi, (f32x4*)(gp + 4));
            }
            // xd (1152 u16x8) on all threads
            #pragma unroll
            for (int it = 0; it < 3; ++it) {
                int v = tid + it * 512;
                if (v < 1152) {
                    int m = v / 144, wi = v - m * 144;
                    u16x8 h = *(const u16x8*)&ostage[m][wi * 8];
                    float* gp = out_xd + (size_t)(m0 + m) * 2304 + t * 1152 + wi * 8;
                    f32x4 lo, hi;
                    lo[0]=bf2f(h[0]); lo[1]=bf2f(h[1]); lo[2]=bf2f(h[2]); lo[3]=bf2f(h[3]);
                    hi[0]=bf2f(h[4]); hi[1]=bf2f(h[5]); hi[2]=bf2f(h[6]); hi[3]=bf2f(h[7]);
                    __builtin_nontemporal_store(lo, (f32x4*)gp);
                    __builtin_nontemporal_store(hi, (f32x4*)(gp + 4));
                }
            }
        }
        __syncthreads();
    }
}

extern "C" void kernel_launch(void* const* d_in, const int* in_sizes, int n_in,
                              void* d_out, int out_size, void* d_ws, size_t ws_size,
                              hipStream_t stream) {
    const float* xa  = (const float*)d_in[0];
    const float* xv  = (const float*)d_in[1];
    const float* xd  = (const float*)d_in[2];
    const float* Wtt = (const float*)d_in[3];
    const float* Wtr = (const float*)d_in[4];
    const float* Wtd = (const float*)d_in[5];
    const float* Wvd = (const float*)d_in[6];
    const float* Wdv = (const float*)d_in[7];
    unsigned short* ws = (unsigned short*)d_ws;
    float* out = (float*)d_out;

    avd_prep_kernel<<<dim3(128), dim3(512), 0, stream>>>(Wtt, Wtr, Wtd, Wvd, Wdv, ws);
    avd_main_kernel<<<dim3(16384 / TM), dim3(512), 0, stream>>>(xa, xv, xd, ws, out);
}

// Round 6
// 241.742 us; speedup vs baseline: 2.3328x; 1.1076x over previous
//
#include <hip/hip_runtime.h>

typedef __attribute__((ext_vector_type(8))) short bf16x8;
typedef __attribute__((ext_vector_type(4))) unsigned short u16x4;
typedef __attribute__((ext_vector_type(4))) float f32x4;

#define TM 8           // tokens per block

__device__ __forceinline__ unsigned short f2bf(float f) {
    unsigned u = __builtin_bit_cast(unsigned, f);
    u += 0x7FFFu + ((u >> 16) & 1u);        // RNE
    return (unsigned short)(u >> 16);
}
__device__ __forceinline__ float bf2f(unsigned short h) {
    return __builtin_bit_cast(float, (unsigned)h << 16);
}

// ws layout: fragment order. u16 index = (((tile*8 + ks)*6 + w)*64 + lane)*8 + j
// lane = aq*16 + col ; value = Wmat_w[o = tile*16+col][c = ks*32 + aq*8 + j]
// w: 0 WTT, 1 WTD, 2 WVD, 3 WA, 4 WV, 5 WVN.  Total 393216 u16 = 786 KB.
__device__ __forceinline__ int widx(int w, int o, int c) {
    int tile = o >> 4, col = o & 15;
    int ks = c >> 5, aq = (c >> 3) & 3, j = c & 7;
    return (((tile * 8 + ks) * 6 + w) * 64 + aq * 16 + col) * 8 + j;
}

// ---------------- prep: Wa = Wtr(I+Wtt), Wv = Wdv(I-Wtt), bf16 + fragment order ----------------
__global__ __launch_bounds__(512)
void avd_prep_kernel(const float* __restrict__ Wtt, const float* __restrict__ Wtr,
                     const float* __restrict__ Wtd, const float* __restrict__ Wvd,
                     const float* __restrict__ Wdv, unsigned short* __restrict__ ws)
{
    __shared__ float ra[2][256], rv[2][256];
    const int half = threadIdx.x >> 8;          // 0..1
    const int c    = threadIdx.x & 255;
    const int o    = blockIdx.x * 2 + half;
    ra[half][c] = Wtr[o * 256 + c];
    rv[half][c] = Wdv[o * 256 + c];
    __syncthreads();
    float sa = 0.f, sv = 0.f;
    #pragma unroll 8
    for (int k = 0; k < 256; ++k) {
        float w = Wtt[k * 256 + c];             // coalesced across c
        sa += ra[half][k] * w;
        sv += rv[half][k] * w;
    }
    const int idx = o * 256 + c;
    const float wa = Wtr[idx] + sa;             // Wtr(I+Wtt)
    const float wv = Wdv[idx] - sv;             // Wdv(I-Wtt)
    ws[widx(0, o, c)] = f2bf(Wtt[idx]);
    ws[widx(1, o, c)] = f2bf(Wtd[idx]);
    ws[widx(2, o, c)] = f2bf(Wvd[idx]);
    ws[widx(3, o, c)] = f2bf(wa);
    ws[widx(4, o, c)] = f2bf(wv);
    ws[widx(5, o, c)] = f2bf(-wv);
}

// ---------------- main: single-layer fused ----------------
__global__ __launch_bounds__(512, 4)
void avd_main_kernel(const float* __restrict__ xa, const float* __restrict__ xv,
                     const float* __restrict__ xd,
                     const unsigned short* __restrict__ ws,
                     float* __restrict__ out)
{
    // feat row = m*13 + p ; p 0..8: x_d (q=i*3+j), 9: x_a, 10..12: x_v comps.
    // row stride 264 u16 (528 B): staging scatter conflict-light, 16B-aligned rows.
    __shared__ __attribute__((aligned(16))) unsigned short feat[104][264];     // 54.9 KB
    __shared__ __attribute__((aligned(16))) unsigned short ostage[TM][1152];   // 18 KB xd
    __shared__ __attribute__((aligned(16))) unsigned short osA[TM][128];       //  2 KB xa
    __shared__ __attribute__((aligned(16))) unsigned short osV[TM][384];       //  6 KB xv

    const int tid  = threadIdx.x;
    const int lane = tid & 63;
    const int wid  = tid >> 6;          // 0..7
    const int m0   = blockIdx.x * TM;

    float* out_xa = out;                 // 16384*256
    float* out_xv = out + 4194304;       // + 16384*256*3
    float* out_xd = out + 16777216;      // + 16384*256*9

    // ---- stage: wave `wid` owns token m = wid; dense f32x4 NT loads, u16 LDS scatter ----
    {
        const int m  = wid;
        const int mx = m << 3;
        // x_d: 576 f32x4 per token, lane does chunks lane + it*64
        const f32x4* srcd = (const f32x4*)(xd + (size_t)(m0 + m) * 2304);
        #pragma unroll
        for (int it = 0; it < 9; ++it) {
            int ch = lane + it * 64;
            f32x4 v = __builtin_nontemporal_load(&srcd[ch]);
            int e0 = ch * 4;
            #pragma unroll
            for (int j = 0; j < 4; ++j) {
                int e = e0 + j;
                int c = e / 9;
                int q = e - c * 9;
                feat[m * 13 + q][c ^ mx] = f2bf(v[j]);
            }
        }
        // x_v: 192 f32x4
        const f32x4* srcv = (const f32x4*)(xv + (size_t)(m0 + m) * 768);
        #pragma unroll
        for (int it = 0; it < 3; ++it) {
            int ch = lane + it * 64;
            f32x4 v = __builtin_nontemporal_load(&srcv[ch]);
            int e0 = ch * 4;
            #pragma unroll
            for (int j = 0; j < 4; ++j) {
                int e = e0 + j;
                int c = e / 3;
                int i = e - c * 3;
                feat[m * 13 + 10 + i][c ^ mx] = f2bf(v[j]);
            }
        }
        // x_a: 64 f32x4
        {
            f32x4 v = __builtin_nontemporal_load(&((const f32x4*)(xa + (size_t)(m0 + m) * 256))[lane]);
            #pragma unroll
            for (int j = 0; j < 4; ++j)
                feat[m * 13 + 9][(lane * 4 + j) ^ mx] = f2bf(v[j]);
        }
    }
    __syncthreads();

    const int am  = lane & 7;    // A-frag token row (rows 8..15 duplicate 0..7)
    const int aq  = lane >> 4;   // k-quarter
    const int col = lane & 15;   // output channel within tile

    #pragma unroll 1
    for (int t = 0; t < 2; ++t) {
        const int o = t * 128 + wid * 16 + col;

        // acc 0..8: t[q]; 9: delta; 10..12: w (cross); 13: xa-delta; 14..16: xv-delta
        f32x4 acc[17];
        #pragma unroll
        for (int p = 0; p < 17; ++p) acc[p] = (f32x4){0.f, 0.f, 0.f, 0.f};

        #pragma unroll 2
        for (int ks = 0; ks < 8; ++ks) {
            const int csw = (ks * 32 + aq * 8) ^ (am << 3);
            bf16x8 a[13];
            #pragma unroll
            for (int p = 0; p < 13; ++p)
                a[p] = *(const bf16x8*)&feat[am * 13 + p][csw];

            // dense fragment-ordered weight loads: 16 B/lane contiguous per matrix
            const unsigned short* wsb = ws + ((((t * 8 + wid) * 8 + ks) * 6) * 64 + lane) * 8;
            bf16x8 b_tt = *(const bf16x8*)(wsb + 0 * 512);
            bf16x8 b_td = *(const bf16x8*)(wsb + 1 * 512);
            bf16x8 b_vd = *(const bf16x8*)(wsb + 2 * 512);
            bf16x8 b_wa = *(const bf16x8*)(wsb + 3 * 512);
            bf16x8 b_wv = *(const bf16x8*)(wsb + 4 * 512);
            bf16x8 b_wn = *(const bf16x8*)(wsb + 5 * 512);

            #pragma unroll
            for (int q = 0; q < 9; ++q)
                acc[q] = __builtin_amdgcn_mfma_f32_16x16x32_bf16(a[q], b_tt, acc[q], 0, 0, 0);
            acc[9]  = __builtin_amdgcn_mfma_f32_16x16x32_bf16(a[9],  b_td, acc[9],  0, 0, 0);
            acc[10] = __builtin_amdgcn_mfma_f32_16x16x32_bf16(a[10], b_vd, acc[10], 0, 0, 0);
            acc[11] = __builtin_amdgcn_mfma_f32_16x16x32_bf16(a[11], b_vd, acc[11], 0, 0, 0);
            acc[12] = __builtin_amdgcn_mfma_f32_16x16x32_bf16(a[12], b_vd, acc[12], 0, 0, 0);
            acc[13] = __builtin_amdgcn_mfma_f32_16x16x32_bf16(a[0], b_wa, acc[13], 0, 0, 0);
            acc[13] = __builtin_amdgcn_mfma_f32_16x16x32_bf16(a[4], b_wa, acc[13], 0, 0, 0);
            acc[13] = __builtin_amdgcn_mfma_f32_16x16x32_bf16(a[8], b_wa, acc[13], 0, 0, 0);
            acc[14] = __builtin_amdgcn_mfma_f32_16x16x32_bf16(a[5], b_wv, acc[14], 0, 0, 0);
            acc[14] = __builtin_amdgcn_mfma_f32_16x16x32_bf16(a[7], b_wn, acc[14], 0, 0, 0);
            acc[15] = __builtin_amdgcn_mfma_f32_16x16x32_bf16(a[6], b_wv, acc[15], 0, 0, 0);
            acc[15] = __builtin_amdgcn_mfma_f32_16x16x32_bf16(a[2], b_wn, acc[15], 0, 0, 0);
            acc[16] = __builtin_amdgcn_mfma_f32_16x16x32_bf16(a[1], b_wv, acc[16], 0, 0, 0);
            acc[16] = __builtin_amdgcn_mfma_f32_16x16x32_bf16(a[3], b_wn, acc[16], 0, 0, 0);
        }

        // epilogue: all lanes. lane<32 -> r=0,1 ; lane>=32 -> r=2,3 (duplicate-held rows)
        {
            const int hi = (lane >> 4) & 1;
            const int ol = o & 127;
#define EPI(R)                                                                  \
            {                                                                   \
                const int m   = hi * 4 + (R);                                   \
                const int cso = o ^ (m << 3);                                   \
                float d[9];                                                     \
                _Pragma("unroll")                                               \
                for (int q = 0; q < 9; ++q) d[q] = bf2f(feat[m * 13 + q][cso]); \
                const float delta = acc[9][(R)];                                \
                const float w0 = acc[10][(R)], w1 = acc[11][(R)], w2 = acc[12][(R)]; \
                unsigned short* os = &ostage[m][ol * 9];                        \
                os[0] = f2bf(d[0] + acc[0][(R)] + delta);                       \
                os[1] = f2bf(d[1] + acc[3][(R)] - w2);                          \
                os[2] = f2bf(d[2] + acc[6][(R)] + w1);                          \
                os[3] = f2bf(d[3] + acc[1][(R)] + w2);                          \
                os[4] = f2bf(d[4] + acc[4][(R)] + delta);                       \
                os[5] = f2bf(d[5] + acc[7][(R)] - w0);                          \
                os[6] = f2bf(d[6] + acc[2][(R)] - w1);                          \
                os[7] = f2bf(d[7] + acc[5][(R)] + w0);                          \
                os[8] = f2bf(d[8] + acc[8][(R)] + delta);                       \
                osA[m][ol] = f2bf(bf2f(feat[m * 13 + 9][cso]) + acc[13][(R)]);  \
                osV[m][ol * 3 + 0] = f2bf(bf2f(feat[m * 13 + 10][cso]) + acc[14][(R)]); \
                osV[m][ol * 3 + 1] = f2bf(bf2f(feat[m * 13 + 11][cso]) + acc[15][(R)]); \
                osV[m][ol * 3 + 2] = f2bf(bf2f(feat[m * 13 + 12][cso]) + acc[16][(R)]); \
            }
            if (lane < 32) { EPI(0); EPI(1); }
            else           { EPI(2); EPI(3); }
#undef EPI
        }
        __syncthreads();

        // ---- drains: every store instruction = 64 lanes x 16 B contiguous ----
        // xd: 2304 f32x4 chunks (8 tokens x 288)
        #pragma unroll
        for (int it = 0; it < 5; ++it) {
            int cidx = tid + it * 512;
            if (cidx < 2304) {
                int mm = cidx / 288;
                int wi = cidx - mm * 288;
                u16x4 h = *(const u16x4*)(&ostage[0][0] + cidx * 4);
                f32x4 v = {bf2f(h[0]), bf2f(h[1]), bf2f(h[2]), bf2f(h[3])};
                float* gp = out_xd + (size_t)(m0 + mm) * 2304 + t * 1152 + wi * 4;
                __builtin_nontemporal_store(v, (f32x4*)gp);
            }
        }
        // xa: 256 chunks (8 x 32)
        if (tid < 256) {
            int mm = tid >> 5, wi = tid & 31;
            u16x4 h = *(const u16x4*)(&osA[0][0] + tid * 4);
            f32x4 v = {bf2f(h[0]), bf2f(h[1]), bf2f(h[2]), bf2f(h[3])};
            float* gp = out_xa + (size_t)(m0 + mm) * 256 + t * 128 + wi * 4;
            __builtin_nontemporal_store(v, (f32x4*)gp);
        }
        // xv: 768 chunks (8 x 96)
        #pragma unroll
        for (int it = 0; it < 2; ++it) {
            int cidx = tid + it * 512;
            if (cidx < 768) {
                int mm = cidx / 96;
                int wi = cidx - mm * 96;
                u16x4 h = *(const u16x4*)(&osV[0][0] + cidx * 4);
                f32x4 v = {bf2f(h[0]), bf2f(h[1]), bf2f(h[2]), bf2f(h[3])};
                float* gp = out_xv + (size_t)(m0 + mm) * 768 + t * 384 + wi * 4;
                __builtin_nontemporal_store(v, (f32x4*)gp);
            }
        }
        __syncthreads();
    }
}

extern "C" void kernel_launch(void* const* d_in, const int* in_sizes, int n_in,
                              void* d_out, int out_size, void* d_ws, size_t ws_size,
                              hipStream_t stream) {
    const float* xa  = (const float*)d_in[0];
    const float* xv  = (const float*)d_in[1];
    const float* xd  = (const float*)d_in[2];
    const float* Wtt = (const float*)d_in[3];
    const float* Wtr = (const float*)d_in[4];
    const float* Wtd = (const float*)d_in[5];
    const float* Wvd = (const float*)d_in[6];
    const float* Wdv = (const float*)d_in[7];
    unsigned short* ws = (unsigned short*)d_ws;
    float* out = (float*)d_out;

    avd_prep_kernel<<<dim3(128), dim3(512), 0, stream>>>(Wtt, Wtr, Wtd, Wvd, Wdv, ws);
    avd_main_kernel<<<dim3(16384 / TM), dim3(512), 0, stream>>>(xa, xv, xd, ws, out);
}